// Round 3
// baseline (2044.211 us; speedup 1.0000x reference)
//
#include <hip/hip_runtime.h>

typedef unsigned short u16;
typedef unsigned int   u32;

#define LOGM 4.852030263919617f

// workspace layout (float offsets)
constexpr int WS_PMAX = 0;        // 128*16 floats (per-combo partial max of logk)
constexpr int WS_K1   = 2048;     // 128*128 floats (k1sum, atomic-accumulated)
constexpr int WS_KV   = 18432;    // 128*128*64 floats (kv, atomic-accumulated)
constexpr int WS_PHIK = 1067008;  // u16 region: 128 combos * 1056 rows * 128 (phi_k bf16)

__device__ __forceinline__ float b2f(u16 u){ union { u32 i; float f; } x; x.i = ((u32)u) << 16; return x.f; }
__device__ __forceinline__ u16 f2b(float f){ union { float f; u32 i; } x; x.f = f; return (u16)((x.i + 0x7fffu + ((x.i >> 16) & 1u)) >> 16); }

// ---------------- K1: per-combo global max of logk over (s, m) ----------------
// grid (16 tiles of 256 keys, 128 combos), 256 threads; thread = one key row
__global__ __launch_bounds__(256) void k_stab(const float* __restrict__ key,
                                              const float* __restrict__ proj,
                                              float* __restrict__ ws){
  __shared__ __align__(16) float projs[128*64];
  __shared__ float red[4];
  const int tid = threadIdx.x;
  const int tile = blockIdx.x, combo = blockIdx.y;
  const int c = combo >> 5, b = (combo >> 3) & 3, h = combo & 7;
  const float4* p4 = (const float4*)(proj + c*8192);
  float4* ps4 = (float4*)projs;
  #pragma unroll
  for(int i=0;i<8;i++) ps4[tid + 256*i] = p4[tid + 256*i];
  __syncthreads();
  const int s = tile*256 + tid;
  const float4* kr = (const float4*)(key + (((size_t)b*4096 + s)*8 + h)*64);
  float kreg[64];
  #pragma unroll
  for(int i=0;i<16;i++){
    float4 u = kr[i];
    kreg[4*i+0]=u.x; kreg[4*i+1]=u.y; kreg[4*i+2]=u.z; kreg[4*i+3]=u.w;
  }
  float ksq = 0.f;
  #pragma unroll
  for(int e=0;e<64;e++) ksq = fmaf(kreg[e], kreg[e], ksq);
  ksq *= 0.5f;
  float mx = -3e38f;
  for(int m=0;m<128;m++){
    const float4* pr = (const float4*)(projs + m*64);   // wave-uniform -> broadcast
    float d0=0.f,d1=0.f,d2=0.f,d3=0.f;
    #pragma unroll
    for(int i=0;i<16;i++){
      float4 p = pr[i];
      d0 = fmaf(kreg[4*i+0], p.x, d0);
      d1 = fmaf(kreg[4*i+1], p.y, d1);
      d2 = fmaf(kreg[4*i+2], p.z, d2);
      d3 = fmaf(kreg[4*i+3], p.w, d3);
    }
    mx = fmaxf(mx, (d0+d1)+(d2+d3) - ksq);
  }
  #pragma unroll
  for(int o=1;o<64;o<<=1) mx = fmaxf(mx, __shfl_xor(mx, o));
  if((tid & 63) == 0) red[tid >> 6] = mx;
  __syncthreads();
  if(tid == 0) ws[WS_PMAX + combo*16 + tile] = fmaxf(fmaxf(red[0],red[1]), fmaxf(red[2],red[3]));
}

// ---------------- K2: phi_k, kv = phi_k^T v, k1sum; store phi_k (s<1056) ----------------
// grid (4 key-ranges of 1024, 128 combos), 256 threads
__global__ __launch_bounds__(256) void k_kv(const float* __restrict__ key,
                                            const float* __restrict__ val,
                                            const float* __restrict__ proj,
                                            float* __restrict__ ws){
  __shared__ __align__(16) float projs[128*64];
  __shared__ __align__(16) u16 phit[64*136];   // 64 keys x 128 m, padded stride 136 (bf16)
  const int tid = threadIdx.x;
  const int range = blockIdx.x, combo = blockIdx.y;
  const int c = combo >> 5, b = (combo >> 3) & 3, h = combo & 7;
  const float4* p4 = (const float4*)(proj + c*8192);
  float4* ps4 = (float4*)projs;
  #pragma unroll
  for(int i=0;i<8;i++) ps4[tid + 256*i] = p4[tid + 256*i];
  float stab = -3e38f;
  #pragma unroll
  for(int i=0;i<16;i++) stab = fmaxf(stab, ws[WS_PMAX + combo*16 + i]);
  __syncthreads();
  const int lane = tid & 63, mg = tid >> 6;   // phi phase: thread = (key lane, m-group = wave)
  const int mkv = tid & 127, dh = tid >> 7;   // kv  phase: thread = (m, d-half)
  float acc[32];
  #pragma unroll
  for(int i=0;i<32;i++) acc[i] = 0.f;
  float k1p = 0.f;
  u16* phikg = ((u16*)(ws + WS_PHIK)) + (size_t)combo*1056*128;
  for(int t0=0;t0<16;t0++){
    const int s0 = range*1024 + t0*64;
    { // ---- phi phase ----
      const float4* kr = (const float4*)(key + (((size_t)b*4096 + (s0+lane))*8 + h)*64);
      float kreg[64];
      #pragma unroll
      for(int i=0;i<16;i++){
        float4 u = kr[i];
        kreg[4*i+0]=u.x; kreg[4*i+1]=u.y; kreg[4*i+2]=u.z; kreg[4*i+3]=u.w;
      }
      float ksq = 0.f;
      #pragma unroll
      for(int e=0;e<64;e++) ksq = fmaf(kreg[e], kreg[e], ksq);
      ksq *= 0.5f;
      u32* prow = ((u32*)phit) + lane*68;
      for(int j=0;j<32;j+=2){
        const int m = mg*32 + j;
        const float4* pr0 = (const float4*)(projs + m*64);       // wave-uniform
        const float4* pr1 = (const float4*)(projs + m*64 + 64);
        float a0=0.f,a1=0.f,b0=0.f,b1=0.f;
        #pragma unroll
        for(int i=0;i<16;i++){
          float4 pA = pr0[i], pB = pr1[i];
          a0 = fmaf(kreg[4*i+0], pA.x, a0); a1 = fmaf(kreg[4*i+1], pA.y, a1);
          a0 = fmaf(kreg[4*i+2], pA.z, a0); a1 = fmaf(kreg[4*i+3], pA.w, a1);
          b0 = fmaf(kreg[4*i+0], pB.x, b0); b1 = fmaf(kreg[4*i+1], pB.y, b1);
          b0 = fmaf(kreg[4*i+2], pB.z, b0); b1 = fmaf(kreg[4*i+3], pB.w, b1);
        }
        float p0 = __expf((a0+a1) - ksq - stab);
        float p1 = __expf((b0+b1) - ksq - stab);
        prow[m>>1] = (u32)f2b(p0) | ((u32)f2b(p1) << 16);
      }
    }
    __syncthreads();
    // ---- coalesced phi_k global writeout (only s < 1056 needed by K3) ----
    if(s0 < 1056){
      #pragma unroll
      for(int i=0;i<8;i++){
        int f4 = (tid + 256*i)*4;
        int sr = f4 >> 7, m0 = f4 & 127;
        if(s0 + sr < 1056){
          ushort4 u = *(const ushort4*)(phit + sr*136 + m0);
          *(ushort4*)(phikg + (size_t)(s0+sr)*128 + m0) = u;
        }
      }
    }
    // ---- kv phase ----
    for(int si=0;si<64;si++){
      float p = b2f(phit[si*136 + mkv]);
      if(dh == 0) k1p += p;
      const float4* vr = (const float4*)(val + (((size_t)b*4096 + (s0+si))*8 + h)*64 + dh*32);
      #pragma unroll
      for(int i=0;i<8;i++){
        float4 u = vr[i];  // wave-uniform address -> broadcast, L1 hit
        acc[4*i+0] = fmaf(p, u.x, acc[4*i+0]);
        acc[4*i+1] = fmaf(p, u.y, acc[4*i+1]);
        acc[4*i+2] = fmaf(p, u.z, acc[4*i+2]);
        acc[4*i+3] = fmaf(p, u.w, acc[4*i+3]);
      }
    }
    __syncthreads();
  }
  float* kvg = ws + WS_KV + (size_t)combo*8192 + mkv*64 + dh*32;
  #pragma unroll
  for(int i=0;i<32;i++) atomicAdd(kvg + i, acc[i]);
  if(dh == 0) atomicAdd(ws + WS_K1 + combo*128 + mkv, k1p);
}

// ---------------- K3: fused query-side + local window + combine ----------------
// grid (16 q-tiles of 64, 128 combos), 256 threads: 4 threads per query (h4 = tid&3)
__global__ __launch_bounds__(256) void k_main(const float* __restrict__ qry,
                                              const float* __restrict__ key,
                                              const float* __restrict__ val,
                                              const float* __restrict__ proj,
                                              float* __restrict__ ws,
                                              float* __restrict__ out){
  __shared__ __align__(16) u16 projs[128*72];    // bf16, padded stride 72
  __shared__ __align__(16) float phiq[64*132];   // fp32 phi_q rows, padded stride 132
  const int tid = threadIdx.x;
  const int qt = blockIdx.x, combo = blockIdx.y;
  const int c = combo >> 5, b = (combo >> 3) & 3, h = combo & 7;
  const float4* p4 = (const float4*)(proj + c*8192);
  #pragma unroll
  for(int i=0;i<8;i++){
    float4 u = p4[tid + 256*i];
    int flat = (tid + 256*i)*4;
    int m = flat >> 6, e = flat & 63;
    ushort4 pk;
    pk.x = f2b(u.x); pk.y = f2b(u.y); pk.z = f2b(u.z); pk.w = f2b(u.w);
    *(ushort4*)(projs + m*72 + e) = pk;
  }
  float stab_k = -3e38f;
  #pragma unroll
  for(int i=0;i<16;i++) stab_k = fmaxf(stab_k, ws[WS_PMAX + combo*16 + i]);
  __syncthreads();
  const int l = tid >> 2, h4 = tid & 3;
  const int lg = qt*64 + l;                 // chunk-local position (drives the window!)
  const float4* qr = (const float4*)(qry + (((size_t)b*4096 + (c*1024 + lg))*8 + h)*64);
  float qreg[64];
  #pragma unroll
  for(int i=0;i<16;i++){
    float4 u = qr[i];
    qreg[4*i+0]=u.x; qreg[4*i+1]=u.y; qreg[4*i+2]=u.z; qreg[4*i+3]=u.w;
  }
  float qsq = 0.f;
  #pragma unroll
  for(int e=0;e<64;e++) qsq = fmaf(qreg[e], qreg[e], qsq);
  qsq *= 0.5f;
  float* myrow = phiq + l*132;
  float mmax = -3e38f;
  // logq into LDS row (m = 4j+h4 interleave keeps proj reads conflict-free)
  for(int j=0;j<32;j++){
    const int m = 4*j + h4;
    const ushort4* pr = (const ushort4*)(projs + m*72);
    float d0=0.f,d1=0.f,d2=0.f,d3=0.f;
    #pragma unroll
    for(int i=0;i<16;i++){
      ushort4 p = pr[i];
      d0 = fmaf(qreg[4*i+0], b2f(p.x), d0);
      d1 = fmaf(qreg[4*i+1], b2f(p.y), d1);
      d2 = fmaf(qreg[4*i+2], b2f(p.z), d2);
      d3 = fmaf(qreg[4*i+3], b2f(p.w), d3);
    }
    float lq = (d0+d1)+(d2+d3) - qsq;
    myrow[m] = lq;
    mmax = fmaxf(mmax, lq);
  }
  mmax = fmaxf(mmax, __shfl_xor(mmax, 1));
  mmax = fmaxf(mmax, __shfl_xor(mmax, 2));
  const float pls = mmax + stab_k - LOGM;
  float lr1p = 0.f;
  const float* k1g = ws + WS_K1 + combo*128;
  for(int j=0;j<32;j++){
    const int m = 4*j + h4;
    float ph = __expf(myrow[m] - mmax);
    myrow[m] = ph;
    lr1p = fmaf(ph, k1g[m], lr1p);
  }
  __syncthreads();
  // pass 1: window scores + dots_p (keys s = lg-16 .. lg+15, clipped at 0)
  float sc[8], dp[8];
  const u16* phikg = ((const u16*)(ws + WS_PHIK)) + (size_t)combo*1056*128;
  #pragma unroll
  for(int i=0;i<8;i++){
    const int s = lg - 16 + h4*8 + i;
    float sci = -1e30f, dpi = 0.f;
    if(s >= 0){
      const float4* kr = (const float4*)(key + (((size_t)b*4096 + s)*8 + h)*64);
      float d0=0.f,d1=0.f,d2=0.f,d3=0.f;
      #pragma unroll
      for(int t=0;t<16;t++){
        float4 u = kr[t];
        d0 = fmaf(qreg[4*t+0], u.x, d0);
        d1 = fmaf(qreg[4*t+1], u.y, d1);
        d2 = fmaf(qreg[4*t+2], u.z, d2);
        d3 = fmaf(qreg[4*t+3], u.w, d3);
      }
      sci = (d0+d1)+(d2+d3);
      const ushort4* pk = (const ushort4*)(phikg + (size_t)s*128);
      float e0=0.f,e1=0.f,e2=0.f,e3=0.f;
      #pragma unroll
      for(int t=0;t<32;t++){
        ushort4 u = pk[t];
        e0 = fmaf(myrow[4*t+0], b2f(u.x), e0);
        e1 = fmaf(myrow[4*t+1], b2f(u.y), e1);
        e2 = fmaf(myrow[4*t+2], b2f(u.z), e2);
        e3 = fmaf(myrow[4*t+3], b2f(u.w), e3);
      }
      dpi = (e0+e1)+(e2+e3);
    }
    sc[i] = sci; dp[i] = dpi;
  }
  // reductions across the query's 4 threads (lanes 4l..4l+3)
  float m1 = sc[0];
  #pragma unroll
  for(int i=1;i<8;i++) m1 = fmaxf(m1, sc[i]);
  m1 = fmaxf(m1, __shfl_xor(m1, 1));
  m1 = fmaxf(m1, __shfl_xor(m1, 2));
  float se = 0.f, win = 0.f;
  #pragma unroll
  for(int i=0;i<8;i++){ se += __expf(sc[i] - m1); win += dp[i]; }
  se += __shfl_xor(se, 1);  se += __shfl_xor(se, 2);
  win += __shfl_xor(win, 1); win += __shfl_xor(win, 2);
  float lr1 = lr1p;
  lr1 += __shfl_xor(lr1, 1); lr1 += __shfl_xor(lr1, 2);
  const float qk_lse = m1 + __logf(se);
  const float lrem = fmaxf(lr1 - win, 1e-24f);
  const float bb = __logf(lrem) + pls;
  const float ln = fmaxf(qk_lse, bb) + log1pf(__expf(-fabsf(qk_lse - bb)));
  const float scale = __expf(pls - ln);
  // pass 2: out = sum_j (p_j - scale*dots_j) v_j + scale * sum_m phi_q[m] kv[m,:]
  float acc[64];
  #pragma unroll
  for(int d=0;d<64;d++) acc[d] = 0.f;
  #pragma unroll
  for(int i=0;i<8;i++){
    const int s = lg - 16 + h4*8 + i;
    if(s >= 0){
      const float cj = __expf(sc[i] - ln) - scale * dp[i];
      const float4* vr = (const float4*)(val + (((size_t)b*4096 + s)*8 + h)*64);
      #pragma unroll
      for(int t=0;t<16;t++){
        float4 u = vr[t];
        acc[4*t+0] = fmaf(cj, u.x, acc[4*t+0]);
        acc[4*t+1] = fmaf(cj, u.y, acc[4*t+1]);
        acc[4*t+2] = fmaf(cj, u.z, acc[4*t+2]);
        acc[4*t+3] = fmaf(cj, u.w, acc[4*t+3]);
      }
    }
  }
  const float* kvg = ws + WS_KV + (size_t)combo*8192;
  for(int j=0;j<32;j++){
    const int m = 4*j + h4;
    const float wv = scale * myrow[m];
    const float4* k4 = (const float4*)(kvg + m*64);
    #pragma unroll
    for(int t=0;t<16;t++){
      float4 f = k4[t];
      acc[4*t+0] = fmaf(wv, f.x, acc[4*t+0]);
      acc[4*t+1] = fmaf(wv, f.y, acc[4*t+1]);
      acc[4*t+2] = fmaf(wv, f.z, acc[4*t+2]);
      acc[4*t+3] = fmaf(wv, f.w, acc[4*t+3]);
    }
  }
  __syncthreads();
  // combine the 4 partial acc[] per query through the (now-dead) phi_q row
  if(h4 & 1){
    float* dst = myrow + ((h4 >> 1) * 64);
    #pragma unroll
    for(int d=0;d<64;d++) dst[d] = acc[d];
  }
  __syncthreads();
  if((h4 & 1) == 0){
    const float* src = myrow + ((h4 >> 1) * 64);
    #pragma unroll
    for(int d=0;d<64;d++) acc[d] += src[d];
  }
  __syncthreads();
  if(h4 == 2){
    #pragma unroll
    for(int d=0;d<64;d++) myrow[64 + d] = acc[d];
  }
  __syncthreads();
  if(h4 == 0){
    #pragma unroll
    for(int d=0;d<64;d++) myrow[d] = acc[d] + myrow[64 + d];
  }
  __syncthreads();
  // coalesced fp32 writeout: 64 rows x 64 cols contiguous in out[b,h,t,:]
  const size_t ob = ((((size_t)b*8 + h)*4096) + (size_t)c*1024 + (size_t)qt*64) * 64;
  float4* o4 = (float4*)(out + ob);
  #pragma unroll
  for(int i=0;i<4;i++){
    int f4 = tid + 256*i;
    int row = f4 >> 4;
    int col = (f4 & 15)*4;
    float4 v;
    v.x = phiq[row*132 + col + 0];
    v.y = phiq[row*132 + col + 1];
    v.z = phiq[row*132 + col + 2];
    v.w = phiq[row*132 + col + 3];
    o4[f4] = v;
  }
}

extern "C" void kernel_launch(void* const* d_in, const int* in_sizes, int n_in,
                              void* d_out, int out_size, void* d_ws, size_t ws_size,
                              hipStream_t stream){
  (void)in_sizes; (void)n_in; (void)out_size; (void)ws_size;
  const float* q = (const float*)d_in[0];
  const float* k = (const float*)d_in[1];
  const float* v = (const float*)d_in[2];
  const float* p = (const float*)d_in[3];
  float* out = (float*)d_out;
  float* ws = (float*)d_ws;
  // zero the atomically-accumulated regions (k1sum + kv); everything else is fully overwritten
  hipMemsetAsync(ws + WS_K1, 0, (size_t)(16384 + 1048576)*sizeof(float), stream);
  k_stab<<<dim3(16,128), 256, 0, stream>>>(k, p, ws);
  k_kv  <<<dim3(4,128),  256, 0, stream>>>(k, v, p, ws);
  k_main<<<dim3(16,128), 256, 0, stream>>>(q, k, v, p, ws, out);
}

// Round 4
// 1062.910 us; speedup vs baseline: 1.9232x; 1.9232x over previous
//
#include <hip/hip_runtime.h>

typedef unsigned short u16;
typedef unsigned int   u32;
typedef __attribute__((ext_vector_type(8))) short short8;
typedef __attribute__((ext_vector_type(4))) float f32x4;

#define LOGM 4.852030263919617f

// workspace layout (float offsets)
constexpr int WS_PMAX = 0;        // 128 floats (per-combo stabilizer bound)
constexpr int WS_K1   = 2048;     // 128*128 floats (k1sum, atomic-accumulated)
constexpr int WS_KV   = 18432;    // 128*128*64 floats (kv [m][d], atomic-accumulated)
constexpr int WS_PHIK = 1067008;  // u16 region: 128 combos * 1056 rows * 128 (phi_k bf16, [s][m])

__device__ __forceinline__ float b2f(u16 u){ union { u32 i; float f; } x; x.i = ((u32)u) << 16; return x.f; }
__device__ __forceinline__ u16 f2b(float f){ union { float f; u32 i; } x; x.f = f; return (u16)((x.i + 0x7fffu + ((x.i >> 16) & 1u)) >> 16); }

// ================= k_phi: logk MFMA -> phi_k -> ws; kv & k1 MFMA =================
// grid (4 key-quarters of 1024, 128 combos), 256 threads (4 waves)
__global__ __launch_bounds__(256, 2) void k_phi(const float* __restrict__ key,
                                                const float* __restrict__ val,
                                                const float* __restrict__ proj,
                                                float* __restrict__ ws){
  __shared__ __align__(16) u16 phit[128*72];   // [m][key64] bf16, stride 72
  __shared__ __align__(16) u16 vt[64*72];      // [d][key64] bf16, stride 72
  __shared__ float sred[4];
  const int tid = threadIdx.x;
  const int wave = tid >> 6, l = tid & 63;
  const int g = l >> 4, r16 = l & 15;
  const int kq = blockIdx.x, combo = blockIdx.y;
  const int c = combo >> 5, b = (combo >> 3) & 3, h = combo & 7;
  const float* projc = proj + c*8192;

  // stabilizer bound = 0.5 * max_m ||p_m||^2  (>= max logk; deterministic across blocks)
  {
    const float4* pr = (const float4*)(projc + (tid & 127)*64);
    float pn = 0.f;
    #pragma unroll
    for(int i=0;i<16;i++){ float4 u = pr[i]; pn = fmaf(u.x,u.x,fmaf(u.y,u.y,fmaf(u.z,u.z,fmaf(u.w,u.w,pn)))); }
    #pragma unroll
    for(int o=1;o<64;o<<=1) pn = fmaxf(pn, __shfl_xor(pn, o));
    if(l == 0) sred[wave] = pn;
  }
  __syncthreads();
  const float stab = 0.5f * fmaxf(fmaxf(sred[0],sred[1]), fmaxf(sred[2],sred[3]));
  if(kq == 0 && tid == 0) ws[WS_PMAX + combo] = stab;

  // P fragments in registers, hi/lo bf16 split: B[n=m][k=e], lane holds P[mt*16+r16][ks*32+g*8+j]
  short8 ph[8][2], pl[8][2];
  #pragma unroll
  for(int mt=0;mt<8;mt++){
    #pragma unroll
    for(int ks=0;ks<2;ks++){
      const float* pb = projc + (mt*16 + r16)*64 + ks*32 + g*8;
      float4 u0 = *(const float4*)pb;
      float4 u1 = *(const float4*)(pb + 4);
      float x[8] = {u0.x,u0.y,u0.z,u0.w,u1.x,u1.y,u1.z,u1.w};
      #pragma unroll
      for(int j=0;j<8;j++){
        u16 hb = f2b(x[j]);
        ph[mt][ks][j] = (short)hb;
        pl[mt][ks][j] = (short)f2b(x[j] - b2f(hb));
      }
    }
  }

  const f32x4 zero4 = {0.f,0.f,0.f,0.f};
  f32x4 kvacc[2][4];
  #pragma unroll
  for(int i=0;i<2;i++)
    #pragma unroll
    for(int j=0;j<4;j++) kvacc[i][j] = zero4;
  float k1p0 = 0.f, k1p1 = 0.f;
  u16* phikg = ((u16*)(ws + WS_PHIK)) + (size_t)combo*1056*128;

  for(int t0=0;t0<16;t0++){
    const int s_tile = kq*1024 + t0*64;
    // ---- phase 1: logk = K.P^T (split-bf16 MFMA), phi_k -> LDS [m][key] ----
    const int sA = s_tile + wave*16 + r16;
    const float* krow = key + (size_t)(b*4096 + sA)*512 + h*64;
    float areg[16];
    #pragma unroll
    for(int ks=0;ks<2;ks++){
      float4 u0 = *(const float4*)(krow + ks*32 + g*8);
      float4 u1 = *(const float4*)(krow + ks*32 + g*8 + 4);
      areg[ks*8+0]=u0.x; areg[ks*8+1]=u0.y; areg[ks*8+2]=u0.z; areg[ks*8+3]=u0.w;
      areg[ks*8+4]=u1.x; areg[ks*8+5]=u1.y; areg[ks*8+6]=u1.z; areg[ks*8+7]=u1.w;
    }
    float ksq = 0.f;
    #pragma unroll
    for(int e=0;e<16;e++) ksq = fmaf(areg[e], areg[e], ksq);
    ksq += __shfl_xor(ksq, 16);
    ksq += __shfl_xor(ksq, 32);
    ksq *= 0.5f;                       // full 0.5*||k||^2 for row r16 (this wave's tile)
    short8 ah[2], al[2];
    #pragma unroll
    for(int ks=0;ks<2;ks++){
      #pragma unroll
      for(int j=0;j<8;j++){
        float x = areg[ks*8+j];
        u16 hb = f2b(x);
        ah[ks][j] = (short)hb;
        al[ks][j] = (short)f2b(x - b2f(hb));
      }
    }
    f32x4 acc[8];
    #pragma unroll
    for(int mt=0;mt<8;mt++) acc[mt] = zero4;
    #pragma unroll
    for(int ks=0;ks<2;ks++){
      #pragma unroll
      for(int mt=0;mt<8;mt++){
        acc[mt] = __builtin_amdgcn_mfma_f32_16x16x32_bf16(ah[ks], ph[mt][ks], acc[mt], 0, 0, 0);
        acc[mt] = __builtin_amdgcn_mfma_f32_16x16x32_bf16(ah[ks], pl[mt][ks], acc[mt], 0, 0, 0);
        acc[mt] = __builtin_amdgcn_mfma_f32_16x16x32_bf16(al[ks], ph[mt][ks], acc[mt], 0, 0, 0);
      }
    }
    // ksq for C rows (row = 4*g + rr)
    const float kc0 = __shfl(ksq, 4*g + 0);
    const float kc1 = __shfl(ksq, 4*g + 1);
    const float kc2 = __shfl(ksq, 4*g + 2);
    const float kc3 = __shfl(ksq, 4*g + 3);
    #pragma unroll
    for(int mt=0;mt<8;mt++){
      ushort4 pw;
      pw.x = f2b(__expf(acc[mt][0] - kc0 - stab));
      pw.y = f2b(__expf(acc[mt][1] - kc1 - stab));
      pw.z = f2b(__expf(acc[mt][2] - kc2 - stab));
      pw.w = f2b(__expf(acc[mt][3] - kc3 - stab));
      *(ushort4*)(phit + (mt*16 + r16)*72 + wave*16 + 4*g) = pw;
    }
    __syncthreads();
    // ---- phase 1.5: phi_k writeout to ws [s][m] (only s<1056 needed downstream) ----
    if(s_tile < 1056){
      const int m = tid & 127, kh = tid >> 7;
      for(int kk=0;kk<32;kk++){
        int skey = kh*32 + kk, gs = s_tile + skey;
        if(gs < 1056) phikg[(size_t)gs*128 + m] = phit[m*72 + skey];
      }
    }
    // ---- phase 2: V tile transpose -> LDS [d][key] bf16 ----
    #pragma unroll
    for(int i=0;i<4;i++){
      int flat = tid + 256*i;
      int sv = flat >> 4, d4 = (flat & 15)*4;
      const float4 u = *(const float4*)(val + (size_t)(b*4096 + s_tile + sv)*512 + h*64 + d4);
      vt[(d4+0)*72 + sv] = f2b(u.x);
      vt[(d4+1)*72 + sv] = f2b(u.y);
      vt[(d4+2)*72 + sv] = f2b(u.z);
      vt[(d4+3)*72 + sv] = f2b(u.w);
    }
    __syncthreads();
    // ---- phase 3: kv += phi_k^T.V, k1 += col-sums (wave owns mtiles 2w,2w+1) ----
    #pragma unroll
    for(int ks=0;ks<2;ks++){
      short8 af0 = *(const short8*)(phit + ((2*wave+0)*16 + r16)*72 + ks*32 + g*8);
      short8 af1 = *(const short8*)(phit + ((2*wave+1)*16 + r16)*72 + ks*32 + g*8);
      short8 bf[4];
      #pragma unroll
      for(int dt=0;dt<4;dt++) bf[dt] = *(const short8*)(vt + (dt*16 + r16)*72 + ks*32 + g*8);
      #pragma unroll
      for(int dt=0;dt<4;dt++){
        kvacc[0][dt] = __builtin_amdgcn_mfma_f32_16x16x32_bf16(af0, bf[dt], kvacc[0][dt], 0, 0, 0);
        kvacc[1][dt] = __builtin_amdgcn_mfma_f32_16x16x32_bf16(af1, bf[dt], kvacc[1][dt], 0, 0, 0);
      }
      #pragma unroll
      for(int j=0;j<8;j++){ k1p0 += b2f((u16)af0[j]); k1p1 += b2f((u16)af1[j]); }
    }
    __syncthreads();
  }
  // finalize k1 (reduce over g-groups; lanes 0..15 hold m = mt*16 + l)
  k1p0 += __shfl_xor(k1p0, 16); k1p0 += __shfl_xor(k1p0, 32);
  k1p1 += __shfl_xor(k1p1, 16); k1p1 += __shfl_xor(k1p1, 32);
  if(l < 16){
    atomicAdd(ws + WS_K1 + combo*128 + (2*wave+0)*16 + l, k1p0);
    atomicAdd(ws + WS_K1 + combo*128 + (2*wave+1)*16 + l, k1p1);
  }
  // finalize kv: C-layout row m = (2w+mi)*16 + 4g + rr, col d = dt*16 + r16
  #pragma unroll
  for(int mi=0;mi<2;mi++){
    #pragma unroll
    for(int dt=0;dt<4;dt++){
      #pragma unroll
      for(int rr=0;rr<4;rr++){
        int m = (2*wave+mi)*16 + 4*g + rr;
        int d = dt*16 + r16;
        atomicAdd(ws + WS_KV + (size_t)combo*8192 + m*64 + d, kvacc[mi][dt][rr]);
      }
    }
  }
}

// ---------------- K3: fused query-side + local window + combine ----------------
// grid (16 q-tiles of 64, 128 combos), 256 threads: 4 threads per query (h4 = tid&3)
__global__ __launch_bounds__(256) void k_main(const float* __restrict__ qry,
                                              const float* __restrict__ key,
                                              const float* __restrict__ val,
                                              const float* __restrict__ proj,
                                              float* __restrict__ ws,
                                              float* __restrict__ out){
  __shared__ __align__(16) u16 win[96*130];      // phase A: projs bf16 (stride 72); phase B: phi_k window (stride 130)
  __shared__ __align__(16) float phiq[64*132];   // fp32 phi_q rows, padded stride 132
  u16* projs = win;
  const int tid = threadIdx.x;
  const int qt = blockIdx.x, combo = blockIdx.y;
  const int c = combo >> 5, b = (combo >> 3) & 3, h = combo & 7;
  const float4* p4 = (const float4*)(proj + c*8192);
  #pragma unroll
  for(int i=0;i<8;i++){
    float4 u = p4[tid + 256*i];
    int flat = (tid + 256*i)*4;
    int m = flat >> 6, e = flat & 63;
    ushort4 pk;
    pk.x = f2b(u.x); pk.y = f2b(u.y); pk.z = f2b(u.z); pk.w = f2b(u.w);
    *(ushort4*)(projs + m*72 + e) = pk;
  }
  const float stab_k = ws[WS_PMAX + combo];
  __syncthreads();
  const int l = tid >> 2, h4 = tid & 3;
  const int lg = qt*64 + l;                 // chunk-local position (drives the window!)
  const float4* qr = (const float4*)(qry + (((size_t)b*4096 + (c*1024 + lg))*8 + h)*64);
  float qreg[64];
  #pragma unroll
  for(int i=0;i<16;i++){
    float4 u = qr[i];
    qreg[4*i+0]=u.x; qreg[4*i+1]=u.y; qreg[4*i+2]=u.z; qreg[4*i+3]=u.w;
  }
  float qsq = 0.f;
  #pragma unroll
  for(int e=0;e<64;e++) qsq = fmaf(qreg[e], qreg[e], qsq);
  qsq *= 0.5f;
  float* myrow = phiq + l*132;
  float mmax = -3e38f;
  // logq into LDS row (m = 4j+h4 interleave keeps proj reads conflict-free)
  for(int j=0;j<32;j++){
    const int m = 4*j + h4;
    const ushort4* pr = (const ushort4*)(projs + m*72);
    float d0=0.f,d1=0.f,d2=0.f,d3=0.f;
    #pragma unroll
    for(int i=0;i<16;i++){
      ushort4 p = pr[i];
      d0 = fmaf(qreg[4*i+0], b2f(p.x), d0);
      d1 = fmaf(qreg[4*i+1], b2f(p.y), d1);
      d2 = fmaf(qreg[4*i+2], b2f(p.z), d2);
      d3 = fmaf(qreg[4*i+3], b2f(p.w), d3);
    }
    float lq = (d0+d1)+(d2+d3) - qsq;
    myrow[m] = lq;
    mmax = fmaxf(mmax, lq);
  }
  mmax = fmaxf(mmax, __shfl_xor(mmax, 1));
  mmax = fmaxf(mmax, __shfl_xor(mmax, 2));
  const float pls = mmax + stab_k - LOGM;
  float lr1p = 0.f;
  const float* k1g = ws + WS_K1 + combo*128;
  for(int j=0;j<32;j++){
    const int m = 4*j + h4;
    float ph = __expf(myrow[m] - mmax);
    myrow[m] = ph;
    lr1p = fmaf(ph, k1g[m], lr1p);
  }
  __syncthreads();
  // stage phi_k window rows [qt*64-16, qt*64+80) into LDS (stride 130, ushort2 granules)
  const int s_base = qt*64 - 16;
  const u16* phikg = ((const u16*)(ws + WS_PHIK)) + (size_t)combo*1056*128;
  #pragma unroll
  for(int i=0;i<24;i++){
    int flat = tid + 256*i;          // 6144 ushort2 = 96 rows * 64
    int row = flat >> 6;
    int c2 = (flat & 63)*2;
    int gs = s_base + row;
    if(gs >= 0 && gs < 1056)
      *(ushort2*)(win + row*130 + c2) = *(const ushort2*)(phikg + (size_t)gs*128 + c2);
  }
  __syncthreads();
  // pass 1: window scores + dots_p (keys s = lg-16 .. lg+15, clipped at 0)
  float sc[8], dp[8];
  #pragma unroll
  for(int i=0;i<8;i++){
    const int s = lg - 16 + h4*8 + i;
    float sci = -1e30f, dpi = 0.f;
    if(s >= 0){
      const float4* kr = (const float4*)(key + (((size_t)b*4096 + s)*8 + h)*64);
      float d0=0.f,d1=0.f,d2=0.f,d3=0.f;
      #pragma unroll
      for(int t=0;t<16;t++){
        float4 u = kr[t];
        d0 = fmaf(qreg[4*t+0], u.x, d0);
        d1 = fmaf(qreg[4*t+1], u.y, d1);
        d2 = fmaf(qreg[4*t+2], u.z, d2);
        d3 = fmaf(qreg[4*t+3], u.w, d3);
      }
      sci = (d0+d1)+(d2+d3);
      const u16* pkrow = win + (s - s_base)*130;
      float e0=0.f,e1=0.f,e2=0.f,e3=0.f;
      #pragma unroll
      for(int t=0;t<32;t++){
        ushort2 u0 = *(const ushort2*)(pkrow + 4*t);
        ushort2 u1 = *(const ushort2*)(pkrow + 4*t + 2);
        e0 = fmaf(myrow[4*t+0], b2f(u0.x), e0);
        e1 = fmaf(myrow[4*t+1], b2f(u0.y), e1);
        e2 = fmaf(myrow[4*t+2], b2f(u1.x), e2);
        e3 = fmaf(myrow[4*t+3], b2f(u1.y), e3);
      }
      dpi = (e0+e1)+(e2+e3);
    }
    sc[i] = sci; dp[i] = dpi;
  }
  // reductions across the query's 4 threads (lanes 4l..4l+3)
  float m1 = sc[0];
  #pragma unroll
  for(int i=1;i<8;i++) m1 = fmaxf(m1, sc[i]);
  m1 = fmaxf(m1, __shfl_xor(m1, 1));
  m1 = fmaxf(m1, __shfl_xor(m1, 2));
  float se = 0.f, winp = 0.f;
  #pragma unroll
  for(int i=0;i<8;i++){ se += __expf(sc[i] - m1); winp += dp[i]; }
  se += __shfl_xor(se, 1);  se += __shfl_xor(se, 2);
  winp += __shfl_xor(winp, 1); winp += __shfl_xor(winp, 2);
  float lr1 = lr1p;
  lr1 += __shfl_xor(lr1, 1); lr1 += __shfl_xor(lr1, 2);
  const float qk_lse = m1 + __logf(se);
  const float lrem = fmaxf(lr1 - winp, 1e-37f);
  const float bb = __logf(lrem) + pls;
  const float ln = fmaxf(qk_lse, bb) + log1pf(__expf(-fabsf(qk_lse - bb)));
  const float scale = __expf(pls - ln);
  // pass 2: out = sum_j (p_j - scale*dots_j) v_j + scale * sum_m phi_q[m] kv[m,:]
  float acc[64];
  #pragma unroll
  for(int d=0;d<64;d++) acc[d] = 0.f;
  #pragma unroll
  for(int i=0;i<8;i++){
    const int s = lg - 16 + h4*8 + i;
    if(s >= 0){
      const float cj = __expf(sc[i] - ln) - scale * dp[i];
      const float4* vr = (const float4*)(val + (((size_t)b*4096 + s)*8 + h)*64);
      #pragma unroll
      for(int t=0;t<16;t++){
        float4 u = vr[t];
        acc[4*t+0] = fmaf(cj, u.x, acc[4*t+0]);
        acc[4*t+1] = fmaf(cj, u.y, acc[4*t+1]);
        acc[4*t+2] = fmaf(cj, u.z, acc[4*t+2]);
        acc[4*t+3] = fmaf(cj, u.w, acc[4*t+3]);
      }
    }
  }
  const float* kvg = ws + WS_KV + (size_t)combo*8192;
  for(int j=0;j<32;j++){
    const int m = 4*j + h4;
    const float wv = scale * myrow[m];
    const float4* k4 = (const float4*)(kvg + m*64);
    #pragma unroll
    for(int t=0;t<16;t++){
      float4 f = k4[t];
      acc[4*t+0] = fmaf(wv, f.x, acc[4*t+0]);
      acc[4*t+1] = fmaf(wv, f.y, acc[4*t+1]);
      acc[4*t+2] = fmaf(wv, f.z, acc[4*t+2]);
      acc[4*t+3] = fmaf(wv, f.w, acc[4*t+3]);
    }
  }
  __syncthreads();
  // combine the 4 partial acc[] per query through the (now-dead) phi_q row
  if(h4 & 1){
    float* dst = myrow + ((h4 >> 1) * 64);
    #pragma unroll
    for(int d=0;d<64;d++) dst[d] = acc[d];
  }
  __syncthreads();
  if((h4 & 1) == 0){
    const float* src = myrow + ((h4 >> 1) * 64);
    #pragma unroll
    for(int d=0;d<64;d++) acc[d] += src[d];
  }
  __syncthreads();
  if(h4 == 2){
    #pragma unroll
    for(int d=0;d<64;d++) myrow[64 + d] = acc[d];
  }
  __syncthreads();
  if(h4 == 0){
    #pragma unroll
    for(int d=0;d<64;d++) myrow[d] = acc[d] + myrow[64 + d];
  }
  __syncthreads();
  // coalesced fp32 writeout: 64 rows x 64 cols contiguous in out[b,h,t,:]
  const size_t ob = ((((size_t)b*8 + h)*4096) + (size_t)c*1024 + (size_t)qt*64) * 64;
  float4* o4 = (float4*)(out + ob);
  #pragma unroll
  for(int i=0;i<4;i++){
    int f4 = tid + 256*i;
    int row = f4 >> 4;
    int col = (f4 & 15)*4;
    float4 v;
    v.x = phiq[row*132 + col + 0];
    v.y = phiq[row*132 + col + 1];
    v.z = phiq[row*132 + col + 2];
    v.w = phiq[row*132 + col + 3];
    o4[f4] = v;
  }
}

extern "C" void kernel_launch(void* const* d_in, const int* in_sizes, int n_in,
                              void* d_out, int out_size, void* d_ws, size_t ws_size,
                              hipStream_t stream){
  (void)in_sizes; (void)n_in; (void)out_size; (void)ws_size;
  const float* q = (const float*)d_in[0];
  const float* k = (const float*)d_in[1];
  const float* v = (const float*)d_in[2];
  const float* p = (const float*)d_in[3];
  float* out = (float*)d_out;
  float* ws = (float*)d_ws;
  // zero the atomically-accumulated regions (k1sum + kv)
  hipMemsetAsync(ws + WS_K1, 0, (size_t)(16384 + 1048576)*sizeof(float), stream);
  k_phi <<<dim3(4,128),  256, 0, stream>>>(k, v, p, ws);
  k_main<<<dim3(16,128), 256, 0, stream>>>(q, k, v, p, ws, out);
}

// Round 5
// 694.722 us; speedup vs baseline: 2.9425x; 1.5300x over previous
//
#include <hip/hip_runtime.h>

typedef unsigned short u16;
typedef unsigned int   u32;
typedef __attribute__((ext_vector_type(8))) short short8;
typedef __attribute__((ext_vector_type(4))) float f32x4;

#define LOGM 4.852030263919617f

// workspace layout (float offsets)
constexpr int WS_PMAX = 0;         // 128 floats (per-combo stabilizer bound)
constexpr int WS_K1   = 2048;      // 128*128 floats (k1sum, atomic-accumulated)
constexpr int WS_KV   = 18432;     // 128*128*64 floats (kv [m][d], atomic-accumulated)
constexpr int WS_PHIK = 1067008;   // u16: 128 combos * 1056 * 128 (phi_k bf16, [s][m])
constexpr int WS_PLS  = 9717760;   // 128*1024 floats
constexpr int WS_LR1  = 9848832;   // 128*1024 floats
constexpr int WS_PHIQ = 9979904;   // u16: 128 * 1024 * 128 (phi_q bf16, [q][m])
constexpr int WS_LRV  = 18368512;  // u16: 128 * 1024 * 64 (lr_v bf16, [q][d])
// total 22,562,816 floats = 90.3 MB

__device__ __forceinline__ float b2f(u16 u){ union { u32 i; float f; } x; x.i = ((u32)u) << 16; return x.f; }
__device__ __forceinline__ u16 f2b(float f){ union { float f; u32 i; } x; x.f = f; return (u16)((x.i + 0x7fffu + ((x.i >> 16) & 1u)) >> 16); }

// ================= k_phi: logk MFMA -> phi_k -> ws; kv & k1 MFMA =================
// grid (4 key-quarters of 1024, 128 combos), 256 threads (4 waves)
__global__ __launch_bounds__(256, 2) void k_phi(const float* __restrict__ key,
                                                const float* __restrict__ val,
                                                const float* __restrict__ proj,
                                                float* __restrict__ ws){
  __shared__ __align__(16) u16 phit[128*72];   // [m][key64] bf16, stride 72
  __shared__ __align__(16) u16 vt[64*72];      // [d][key64] bf16, stride 72
  __shared__ float sred[4];
  const int tid = threadIdx.x;
  const int wave = tid >> 6, l = tid & 63;
  const int g = l >> 4, r16 = l & 15;
  const int kq = blockIdx.x, combo = blockIdx.y;
  const int c = combo >> 5, b = (combo >> 3) & 3, h = combo & 7;
  const float* projc = proj + c*8192;

  // stabilizer bound = 0.5 * max_m ||p_m||^2  (>= max logk; deterministic across blocks)
  {
    const float4* pr = (const float4*)(projc + (tid & 127)*64);
    float pn = 0.f;
    #pragma unroll
    for(int i=0;i<16;i++){ float4 u = pr[i]; pn = fmaf(u.x,u.x,fmaf(u.y,u.y,fmaf(u.z,u.z,fmaf(u.w,u.w,pn)))); }
    #pragma unroll
    for(int o=1;o<64;o<<=1) pn = fmaxf(pn, __shfl_xor(pn, o));
    if(l == 0) sred[wave] = pn;
  }
  __syncthreads();
  const float stab = 0.5f * fmaxf(fmaxf(sred[0],sred[1]), fmaxf(sred[2],sred[3]));
  if(kq == 0 && tid == 0) ws[WS_PMAX + combo] = stab;

  // P fragments in registers, hi/lo bf16 split
  short8 ph[8][2], pl[8][2];
  #pragma unroll
  for(int mt=0;mt<8;mt++){
    #pragma unroll
    for(int ks=0;ks<2;ks++){
      const float* pb = projc + (mt*16 + r16)*64 + ks*32 + g*8;
      float4 u0 = *(const float4*)pb;
      float4 u1 = *(const float4*)(pb + 4);
      float x[8] = {u0.x,u0.y,u0.z,u0.w,u1.x,u1.y,u1.z,u1.w};
      #pragma unroll
      for(int j=0;j<8;j++){
        u16 hb = f2b(x[j]);
        ph[mt][ks][j] = (short)hb;
        pl[mt][ks][j] = (short)f2b(x[j] - b2f(hb));
      }
    }
  }

  const f32x4 zero4 = {0.f,0.f,0.f,0.f};
  f32x4 kvacc[2][4];
  #pragma unroll
  for(int i=0;i<2;i++)
    #pragma unroll
    for(int j=0;j<4;j++) kvacc[i][j] = zero4;
  float k1p0 = 0.f, k1p1 = 0.f;
  u16* phikg = ((u16*)(ws + WS_PHIK)) + (size_t)combo*1056*128;

  for(int t0=0;t0<16;t0++){
    const int s_tile = kq*1024 + t0*64;
    const int sA = s_tile + wave*16 + r16;
    const float* krow = key + (size_t)(b*4096 + sA)*512 + h*64;
    float areg[16];
    #pragma unroll
    for(int ks=0;ks<2;ks++){
      float4 u0 = *(const float4*)(krow + ks*32 + g*8);
      float4 u1 = *(const float4*)(krow + ks*32 + g*8 + 4);
      areg[ks*8+0]=u0.x; areg[ks*8+1]=u0.y; areg[ks*8+2]=u0.z; areg[ks*8+3]=u0.w;
      areg[ks*8+4]=u1.x; areg[ks*8+5]=u1.y; areg[ks*8+6]=u1.z; areg[ks*8+7]=u1.w;
    }
    float ksq = 0.f;
    #pragma unroll
    for(int e=0;e<16;e++) ksq = fmaf(areg[e], areg[e], ksq);
    ksq += __shfl_xor(ksq, 16);
    ksq += __shfl_xor(ksq, 32);
    ksq *= 0.5f;
    short8 ah[2], al[2];
    #pragma unroll
    for(int ks=0;ks<2;ks++){
      #pragma unroll
      for(int j=0;j<8;j++){
        float x = areg[ks*8+j];
        u16 hb = f2b(x);
        ah[ks][j] = (short)hb;
        al[ks][j] = (short)f2b(x - b2f(hb));
      }
    }
    f32x4 acc[8];
    #pragma unroll
    for(int mt=0;mt<8;mt++) acc[mt] = zero4;
    #pragma unroll
    for(int ks=0;ks<2;ks++){
      #pragma unroll
      for(int mt=0;mt<8;mt++){
        acc[mt] = __builtin_amdgcn_mfma_f32_16x16x32_bf16(ah[ks], ph[mt][ks], acc[mt], 0, 0, 0);
        acc[mt] = __builtin_amdgcn_mfma_f32_16x16x32_bf16(ah[ks], pl[mt][ks], acc[mt], 0, 0, 0);
        acc[mt] = __builtin_amdgcn_mfma_f32_16x16x32_bf16(al[ks], ph[mt][ks], acc[mt], 0, 0, 0);
      }
    }
    const float kc0 = __shfl(ksq, 4*g + 0);
    const float kc1 = __shfl(ksq, 4*g + 1);
    const float kc2 = __shfl(ksq, 4*g + 2);
    const float kc3 = __shfl(ksq, 4*g + 3);
    #pragma unroll
    for(int mt=0;mt<8;mt++){
      ushort4 pw;
      pw.x = f2b(__expf(acc[mt][0] - kc0 - stab));
      pw.y = f2b(__expf(acc[mt][1] - kc1 - stab));
      pw.z = f2b(__expf(acc[mt][2] - kc2 - stab));
      pw.w = f2b(__expf(acc[mt][3] - kc3 - stab));
      *(ushort4*)(phit + (mt*16 + r16)*72 + wave*16 + 4*g) = pw;
    }
    __syncthreads();
    if(s_tile < 1056){
      const int m = tid & 127, kh = tid >> 7;
      for(int kk=0;kk<32;kk++){
        int skey = kh*32 + kk, gs = s_tile + skey;
        if(gs < 1056) phikg[(size_t)gs*128 + m] = phit[m*72 + skey];
      }
    }
    #pragma unroll
    for(int i=0;i<4;i++){
      int flat = tid + 256*i;
      int sv = flat >> 4, d4 = (flat & 15)*4;
      const float4 u = *(const float4*)(val + (size_t)(b*4096 + s_tile + sv)*512 + h*64 + d4);
      vt[(d4+0)*72 + sv] = f2b(u.x);
      vt[(d4+1)*72 + sv] = f2b(u.y);
      vt[(d4+2)*72 + sv] = f2b(u.z);
      vt[(d4+3)*72 + sv] = f2b(u.w);
    }
    __syncthreads();
    #pragma unroll
    for(int ks=0;ks<2;ks++){
      short8 af0 = *(const short8*)(phit + ((2*wave+0)*16 + r16)*72 + ks*32 + g*8);
      short8 af1 = *(const short8*)(phit + ((2*wave+1)*16 + r16)*72 + ks*32 + g*8);
      short8 bf[4];
      #pragma unroll
      for(int dt=0;dt<4;dt++) bf[dt] = *(const short8*)(vt + (dt*16 + r16)*72 + ks*32 + g*8);
      #pragma unroll
      for(int dt=0;dt<4;dt++){
        kvacc[0][dt] = __builtin_amdgcn_mfma_f32_16x16x32_bf16(af0, bf[dt], kvacc[0][dt], 0, 0, 0);
        kvacc[1][dt] = __builtin_amdgcn_mfma_f32_16x16x32_bf16(af1, bf[dt], kvacc[1][dt], 0, 0, 0);
      }
      #pragma unroll
      for(int j=0;j<8;j++){ k1p0 += b2f((u16)af0[j]); k1p1 += b2f((u16)af1[j]); }
    }
    __syncthreads();
  }
  k1p0 += __shfl_xor(k1p0, 16); k1p0 += __shfl_xor(k1p0, 32);
  k1p1 += __shfl_xor(k1p1, 16); k1p1 += __shfl_xor(k1p1, 32);
  if(l < 16){
    atomicAdd(ws + WS_K1 + combo*128 + (2*wave+0)*16 + l, k1p0);
    atomicAdd(ws + WS_K1 + combo*128 + (2*wave+1)*16 + l, k1p1);
  }
  #pragma unroll
  for(int mi=0;mi<2;mi++){
    #pragma unroll
    for(int dt=0;dt<4;dt++){
      #pragma unroll
      for(int rr=0;rr<4;rr++){
        int m = (2*wave+mi)*16 + 4*g + rr;
        int d = dt*16 + r16;
        atomicAdd(ws + WS_KV + (size_t)combo*8192 + m*64 + d, kvacc[mi][dt][rr]);
      }
    }
  }
}

// ================= k_q: logq MFMA -> phi_q/pls/lr1; lr_v = phi_q . kv MFMA =================
// grid (16 q-tiles of 64, 128 combos), 256 threads (4 waves; wave w owns q rows w*16..w*16+15)
__global__ __launch_bounds__(256, 2) void k_q(const float* __restrict__ qry,
                                              const float* __restrict__ proj,
                                              float* __restrict__ ws){
  __shared__ __align__(16) u16 phiqs[64*136];  // [q][m] bf16, stride 136 (rows 16B-aligned)
  __shared__ __align__(16) u16 kvt[64*136];    // [d][m] bf16
  __shared__ float k1s[128];
  const int tid = threadIdx.x;
  const int wave = tid >> 6, l = tid & 63;
  const int g = l >> 4, r16 = l & 15;
  const int qt = blockIdx.x, combo = blockIdx.y;
  const int c = combo >> 5, b = (combo >> 3) & 3, h = combo & 7;
  const float* projc = proj + c*8192;
  const float stab = ws[WS_PMAX + combo];
  if(tid < 128) k1s[tid] = ws[WS_K1 + combo*128 + tid];
  // stage kv -> [d][m] bf16 transpose
  const float* kvg = ws + WS_KV + (size_t)combo*8192;
  #pragma unroll
  for(int i=0;i<8;i++){
    int flat = tid + 256*i;                  // 2048 float4
    int m = flat >> 4, d4 = (flat & 15)*4;
    float4 u = *(const float4*)(kvg + m*64 + d4);
    kvt[(d4+0)*136 + m] = f2b(u.x);
    kvt[(d4+1)*136 + m] = f2b(u.y);
    kvt[(d4+2)*136 + m] = f2b(u.z);
    kvt[(d4+3)*136 + m] = f2b(u.w);
  }
  // Q A-frags (hi/lo) for rows qt*64 + wave*16 + r16
  const int qrow = qt*64 + wave*16 + r16;
  const float* qr = qry + (size_t)(b*4096 + (c*1024 + qrow))*512 + h*64;
  float areg[16];
  #pragma unroll
  for(int ks=0;ks<2;ks++){
    float4 u0 = *(const float4*)(qr + ks*32 + g*8);
    float4 u1 = *(const float4*)(qr + ks*32 + g*8 + 4);
    areg[ks*8+0]=u0.x; areg[ks*8+1]=u0.y; areg[ks*8+2]=u0.z; areg[ks*8+3]=u0.w;
    areg[ks*8+4]=u1.x; areg[ks*8+5]=u1.y; areg[ks*8+6]=u1.z; areg[ks*8+7]=u1.w;
  }
  float qsq = 0.f;
  #pragma unroll
  for(int e=0;e<16;e++) qsq = fmaf(areg[e], areg[e], qsq);
  qsq += __shfl_xor(qsq, 16);
  qsq += __shfl_xor(qsq, 32);
  qsq *= 0.5f;
  short8 ah[2], al[2];
  #pragma unroll
  for(int ks=0;ks<2;ks++){
    #pragma unroll
    for(int j=0;j<8;j++){
      float x = areg[ks*8+j];
      u16 hb = f2b(x);
      ah[ks][j] = (short)hb;
      al[ks][j] = (short)f2b(x - b2f(hb));
    }
  }
  const f32x4 zero4 = {0.f,0.f,0.f,0.f};
  f32x4 acc[8];
  #pragma unroll
  for(int mt=0;mt<8;mt++) acc[mt] = zero4;
  #pragma unroll
  for(int ks=0;ks<2;ks++){
    #pragma unroll
    for(int mt=0;mt<8;mt++){
      const float* pb = projc + (mt*16 + r16)*64 + ks*32 + g*8;
      float4 u0 = *(const float4*)pb;
      float4 u1 = *(const float4*)(pb + 4);
      float x[8] = {u0.x,u0.y,u0.z,u0.w,u1.x,u1.y,u1.z,u1.w};
      short8 pph, ppl;
      #pragma unroll
      for(int j=0;j<8;j++){
        u16 hb = f2b(x[j]);
        pph[j] = (short)hb;
        ppl[j] = (short)f2b(x[j] - b2f(hb));
      }
      acc[mt] = __builtin_amdgcn_mfma_f32_16x16x32_bf16(ah[ks], pph, acc[mt], 0, 0, 0);
      acc[mt] = __builtin_amdgcn_mfma_f32_16x16x32_bf16(ah[ks], ppl, acc[mt], 0, 0, 0);
      acc[mt] = __builtin_amdgcn_mfma_f32_16x16x32_bf16(al[ks], pph, acc[mt], 0, 0, 0);
    }
  }
  // epilogue in C layout: row q = wave*16 + 4g + r, col m = mt*16 + r16
  float qsr[4];
  #pragma unroll
  for(int r=0;r<4;r++) qsr[r] = __shfl(qsq, 4*g + r);
  float amax[4];
  #pragma unroll
  for(int r=0;r<4;r++){
    float m = -3e38f;
    #pragma unroll
    for(int mt=0;mt<8;mt++) m = fmaxf(m, acc[mt][r]);
    m = fmaxf(m, __shfl_xor(m, 1));
    m = fmaxf(m, __shfl_xor(m, 2));
    m = fmaxf(m, __shfl_xor(m, 4));
    m = fmaxf(m, __shfl_xor(m, 8));
    amax[r] = m;
  }
  float lrp[4] = {0.f,0.f,0.f,0.f};
  #pragma unroll
  for(int mt=0;mt<8;mt++){
    const float k1v = k1s[mt*16 + r16];
    #pragma unroll
    for(int r=0;r<4;r++){
      float phv = __expf(acc[mt][r] - amax[r]);
      phiqs[(wave*16 + 4*g + r)*136 + mt*16 + r16] = f2b(phv);
      lrp[r] = fmaf(phv, k1v, lrp[r]);
    }
  }
  #pragma unroll
  for(int r=0;r<4;r++){
    lrp[r] += __shfl_xor(lrp[r], 1);
    lrp[r] += __shfl_xor(lrp[r], 2);
    lrp[r] += __shfl_xor(lrp[r], 4);
    lrp[r] += __shfl_xor(lrp[r], 8);
  }
  if(r16 == 0){
    #pragma unroll
    for(int r=0;r<4;r++){
      int row = qt*64 + wave*16 + 4*g + r;
      ws[WS_PLS + combo*1024 + row] = amax[r] - qsr[r] + stab - LOGM;
      ws[WS_LR1 + combo*1024 + row] = lrp[r];
    }
  }
  __syncthreads();
  // lr_v = phi_q . kv   (A rows = q via r16, B rows = d via r16, k = m)
  f32x4 lacc[4];
  #pragma unroll
  for(int dt=0;dt<4;dt++) lacc[dt] = zero4;
  #pragma unroll
  for(int ks=0;ks<4;ks++){
    short8 a = *(const short8*)(phiqs + (wave*16 + r16)*136 + ks*32 + g*8);
    #pragma unroll
    for(int dt=0;dt<4;dt++){
      short8 bfr = *(const short8*)(kvt + (dt*16 + r16)*136 + ks*32 + g*8);
      lacc[dt] = __builtin_amdgcn_mfma_f32_16x16x32_bf16(a, bfr, lacc[dt], 0, 0, 0);
    }
  }
  u16* lrvg = ((u16*)(ws + WS_LRV)) + ((size_t)combo*1024 + qt*64)*64;
  #pragma unroll
  for(int dt=0;dt<4;dt++){
    #pragma unroll
    for(int r=0;r<4;r++)
      lrvg[(wave*16 + 4*g + r)*64 + dt*16 + r16] = f2b(lacc[dt][r]);
  }
  // coalesced phi_q export
  u16* phiqg = ((u16*)(ws + WS_PHIQ)) + ((size_t)combo*1024 + qt*64)*128;
  #pragma unroll
  for(int i=0;i<8;i++){
    int flat = tid + 256*i;                 // 2048 ushort4
    int row = flat >> 5, c4 = (flat & 31)*4;
    *(ushort4*)(phiqg + flat*4) = *(const ushort4*)(phiqs + row*136 + c4);
  }
}

// ================= k_main: local window + combine (scalar, slim) =================
// grid (16 q-tiles of 64, 128 combos), 256 threads: 4 threads per query (h4 = tid&3)
__global__ __launch_bounds__(256) void k_main(const float* __restrict__ qry,
                                              const float* __restrict__ key,
                                              const float* __restrict__ val,
                                              float* __restrict__ ws,
                                              float* __restrict__ out){
  __shared__ __align__(16) u16 win[96*136];     // phi_k window [row][m] bf16
  __shared__ __align__(16) u16 phiqs[64*136];   // phi_q [q][m] bf16
  const int tid = threadIdx.x;
  const int qt = blockIdx.x, combo = blockIdx.y;
  const int c = combo >> 5, b = (combo >> 3) & 3, h = combo & 7;
  // stage phi_q (coalesced)
  const u16* phiqg = ((const u16*)(ws + WS_PHIQ)) + ((size_t)combo*1024 + qt*64)*128;
  #pragma unroll
  for(int i=0;i<8;i++){
    int flat = tid + 256*i;
    int row = flat >> 5, c4 = (flat & 31)*4;
    *(ushort4*)(phiqs + row*136 + c4) = *(const ushort4*)(phiqg + flat*4);
  }
  // stage phi_k window rows [qt*64-16, qt*64+80)
  const int s_base = qt*64 - 16;
  const u16* phikg = ((const u16*)(ws + WS_PHIK)) + (size_t)combo*1056*128;
  #pragma unroll
  for(int i=0;i<12;i++){
    int flat = tid + 256*i;                 // 3072 ushort4 = 96 rows * 32
    int row = flat >> 5, c4 = (flat & 31)*4;
    int gs = s_base + row;
    if(gs >= 0)
      *(ushort4*)(win + row*136 + c4) = *(const ushort4*)(phikg + (size_t)gs*128 + c4);
  }
  __syncthreads();
  const int l = tid >> 2, h4 = tid & 3;
  const int lg = qt*64 + l;
  const float4* qr = (const float4*)(qry + (((size_t)b*4096 + (c*1024 + lg))*8 + h)*64);
  float qreg[64];
  #pragma unroll
  for(int i=0;i<16;i++){
    float4 u = qr[i];
    qreg[4*i+0]=u.x; qreg[4*i+1]=u.y; qreg[4*i+2]=u.z; qreg[4*i+3]=u.w;
  }
  const float pls = ws[WS_PLS + combo*1024 + lg];
  const float lr1 = ws[WS_LR1 + combo*1024 + lg];
  const u16* myrow = phiqs + l*136;
  // pass 1: window scores + dots_p
  float sc[8], dp[8];
  #pragma unroll
  for(int i=0;i<8;i++){
    const int s = lg - 16 + h4*8 + i;
    float sci = -1e30f, dpi = 0.f;
    if(s >= 0){
      const float4* kr = (const float4*)(key + (((size_t)b*4096 + s)*8 + h)*64);
      float d0=0.f,d1=0.f,d2=0.f,d3=0.f;
      #pragma unroll
      for(int t=0;t<16;t++){
        float4 u = kr[t];
        d0 = fmaf(qreg[4*t+0], u.x, d0);
        d1 = fmaf(qreg[4*t+1], u.y, d1);
        d2 = fmaf(qreg[4*t+2], u.z, d2);
        d3 = fmaf(qreg[4*t+3], u.w, d3);
      }
      sci = (d0+d1)+(d2+d3);
      const u16* pkrow = win + (s - s_base)*136;
      float e0=0.f,e1=0.f,e2=0.f,e3=0.f;
      #pragma unroll
      for(int t=0;t<16;t++){
        short8 a = *(const short8*)(myrow + 8*t);
        short8 bq = *(const short8*)(pkrow + 8*t);
        e0 = fmaf(b2f((u16)a[0]), b2f((u16)bq[0]), e0);
        e1 = fmaf(b2f((u16)a[1]), b2f((u16)bq[1]), e1);
        e2 = fmaf(b2f((u16)a[2]), b2f((u16)bq[2]), e2);
        e3 = fmaf(b2f((u16)a[3]), b2f((u16)bq[3]), e3);
        e0 = fmaf(b2f((u16)a[4]), b2f((u16)bq[4]), e0);
        e1 = fmaf(b2f((u16)a[5]), b2f((u16)bq[5]), e1);
        e2 = fmaf(b2f((u16)a[6]), b2f((u16)bq[6]), e2);
        e3 = fmaf(b2f((u16)a[7]), b2f((u16)bq[7]), e3);
      }
      dpi = (e0+e1)+(e2+e3);
    }
    sc[i] = sci; dp[i] = dpi;
  }
  // reductions across the query's 4 threads
  float m1 = sc[0];
  #pragma unroll
  for(int i=1;i<8;i++) m1 = fmaxf(m1, sc[i]);
  m1 = fmaxf(m1, __shfl_xor(m1, 1));
  m1 = fmaxf(m1, __shfl_xor(m1, 2));
  float se = 0.f, winp = 0.f;
  #pragma unroll
  for(int i=0;i<8;i++){ se += __expf(sc[i] - m1); winp += dp[i]; }
  se += __shfl_xor(se, 1);  se += __shfl_xor(se, 2);
  winp += __shfl_xor(winp, 1); winp += __shfl_xor(winp, 2);
  const float qk_lse = m1 + __logf(se);
  const float lrem = fmaxf(lr1 - winp, 1e-37f);
  const float bb = __logf(lrem) + pls;
  const float ln = fmaxf(qk_lse, bb) + log1pf(__expf(-fabsf(qk_lse - bb)));
  const float scale = __expf(pls - ln);
  // pass 2: local (p - scale*dots) . V
  float acc[64];
  #pragma unroll
  for(int d=0;d<64;d++) acc[d] = 0.f;
  #pragma unroll
  for(int i=0;i<8;i++){
    const int s = lg - 16 + h4*8 + i;
    if(s >= 0){
      const float cj = __expf(sc[i] - ln) - scale * dp[i];
      const float4* vr = (const float4*)(val + (((size_t)b*4096 + s)*8 + h)*64);
      #pragma unroll
      for(int t=0;t<16;t++){
        float4 u = vr[t];
        acc[4*t+0] = fmaf(cj, u.x, acc[4*t+0]);
        acc[4*t+1] = fmaf(cj, u.y, acc[4*t+1]);
        acc[4*t+2] = fmaf(cj, u.z, acc[4*t+2]);
        acc[4*t+3] = fmaf(cj, u.w, acc[4*t+3]);
      }
    }
  }
  // combine across the query's 4 threads (adjacent lanes) via shuffles
  #pragma unroll
  for(int d=0;d<64;d++){
    acc[d] += __shfl_xor(acc[d], 1);
    acc[d] += __shfl_xor(acc[d], 2);
  }
  // add scale * lr_v for this thread's d-quarter, write out
  const u16* lrvp = ((const u16*)(ws + WS_LRV)) + ((size_t)combo*1024 + lg)*64 + h4*16;
  float* ob = out + ((((size_t)b*8 + h)*4096) + (size_t)c*1024 + lg)*64 + h4*16;
  #pragma unroll
  for(int j=0;j<4;j++){
    ushort4 lv = *(const ushort4*)(lrvp + 4*j);
    float4 o;
    o.x = acc[h4*16 + 4*j + 0] + scale * b2f(lv.x);
    o.y = acc[h4*16 + 4*j + 1] + scale * b2f(lv.y);
    o.z = acc[h4*16 + 4*j + 2] + scale * b2f(lv.z);
    o.w = acc[h4*16 + 4*j + 3] + scale * b2f(lv.w);
    *(float4*)(ob + 4*j) = o;
  }
}

extern "C" void kernel_launch(void* const* d_in, const int* in_sizes, int n_in,
                              void* d_out, int out_size, void* d_ws, size_t ws_size,
                              hipStream_t stream){
  (void)in_sizes; (void)n_in; (void)out_size; (void)ws_size;
  const float* q = (const float*)d_in[0];
  const float* k = (const float*)d_in[1];
  const float* v = (const float*)d_in[2];
  const float* p = (const float*)d_in[3];
  float* out = (float*)d_out;
  float* ws = (float*)d_ws;
  hipMemsetAsync(ws + WS_K1, 0, (size_t)(16384 + 1048576)*sizeof(float), stream);
  k_phi <<<dim3(4,128),  256, 0, stream>>>(k, v, p, ws);
  k_q   <<<dim3(16,128), 256, 0, stream>>>(q, p, ws);
  k_main<<<dim3(16,128), 256, 0, stream>>>(q, k, v, ws, out);
}

// Round 6
// 548.202 us; speedup vs baseline: 3.7289x; 1.2673x over previous
//
#include <hip/hip_runtime.h>

typedef unsigned short u16;
typedef unsigned int   u32;
typedef __attribute__((ext_vector_type(8))) short short8;
typedef __attribute__((ext_vector_type(4))) float f32x4;

#define LOGM 4.852030263919617f

// workspace layout (float offsets)
constexpr int WS_PMAX = 0;         // 128 floats (per-combo stabilizer bound)
constexpr int WS_K1   = 2048;      // 128*128 floats (k1sum, atomic-accumulated)
constexpr int WS_KV   = 18432;     // 128*128*64 floats (kv [m][d], atomic-accumulated)
constexpr int WS_PHIK = 1067008;   // u16: 128 combos * 1056 * 128 (phi_k bf16, [s][m])
constexpr int WS_PLS  = 9717760;   // 128*1024 floats
constexpr int WS_LR1  = 9848832;   // 128*1024 floats
constexpr int WS_PHIQ = 9979904;   // u16: 128 * 1024 * 128 (phi_q bf16, [q][m])
constexpr int WS_LRV  = 18368512;  // u16: 128 * 1024 * 64 (lr_v bf16, [q][d])

__device__ __forceinline__ float b2f(u16 u){ union { u32 i; float f; } x; x.i = ((u32)u) << 16; return x.f; }
__device__ __forceinline__ u16 f2b(float f){ union { float f; u32 i; } x; x.f = f; return (u16)((x.i + 0x7fffu + ((x.i >> 16) & 1u)) >> 16); }

// ================= k_phi: logk MFMA -> phi_k -> ws; kv & k1 MFMA =================
__global__ __launch_bounds__(256, 2) void k_phi(const float* __restrict__ key,
                                                const float* __restrict__ val,
                                                const float* __restrict__ proj,
                                                float* __restrict__ ws){
  __shared__ __align__(16) u16 phit[128*72];   // [m][key64] bf16, stride 72
  __shared__ __align__(16) u16 vt[64*72];      // [d][key64] bf16, stride 72
  __shared__ float sred[4];
  const int tid = threadIdx.x;
  const int wave = tid >> 6, l = tid & 63;
  const int g = l >> 4, r16 = l & 15;
  const int kq = blockIdx.x, combo = blockIdx.y;
  const int c = combo >> 5, b = (combo >> 3) & 3, h = combo & 7;
  const float* projc = proj + c*8192;

  {
    const float4* pr = (const float4*)(projc + (tid & 127)*64);
    float pn = 0.f;
    #pragma unroll
    for(int i=0;i<16;i++){ float4 u = pr[i]; pn = fmaf(u.x,u.x,fmaf(u.y,u.y,fmaf(u.z,u.z,fmaf(u.w,u.w,pn)))); }
    #pragma unroll
    for(int o=1;o<64;o<<=1) pn = fmaxf(pn, __shfl_xor(pn, o));
    if(l == 0) sred[wave] = pn;
  }
  __syncthreads();
  const float stab = 0.5f * fmaxf(fmaxf(sred[0],sred[1]), fmaxf(sred[2],sred[3]));
  if(kq == 0 && tid == 0) ws[WS_PMAX + combo] = stab;

  short8 ph[8][2], pl[8][2];
  #pragma unroll
  for(int mt=0;mt<8;mt++){
    #pragma unroll
    for(int ks=0;ks<2;ks++){
      const float* pb = projc + (mt*16 + r16)*64 + ks*32 + g*8;
      float4 u0 = *(const float4*)pb;
      float4 u1 = *(const float4*)(pb + 4);
      float x[8] = {u0.x,u0.y,u0.z,u0.w,u1.x,u1.y,u1.z,u1.w};
      #pragma unroll
      for(int j=0;j<8;j++){
        u16 hb = f2b(x[j]);
        ph[mt][ks][j] = (short)hb;
        pl[mt][ks][j] = (short)f2b(x[j] - b2f(hb));
      }
    }
  }

  const f32x4 zero4 = {0.f,0.f,0.f,0.f};
  f32x4 kvacc[2][4];
  #pragma unroll
  for(int i=0;i<2;i++)
    #pragma unroll
    for(int j=0;j<4;j++) kvacc[i][j] = zero4;
  float k1p0 = 0.f, k1p1 = 0.f;
  u16* phikg = ((u16*)(ws + WS_PHIK)) + (size_t)combo*1056*128;

  for(int t0=0;t0<16;t0++){
    const int s_tile = kq*1024 + t0*64;
    const int sA = s_tile + wave*16 + r16;
    const float* krow = key + (size_t)(b*4096 + sA)*512 + h*64;
    float areg[16];
    #pragma unroll
    for(int ks=0;ks<2;ks++){
      float4 u0 = *(const float4*)(krow + ks*32 + g*8);
      float4 u1 = *(const float4*)(krow + ks*32 + g*8 + 4);
      areg[ks*8+0]=u0.x; areg[ks*8+1]=u0.y; areg[ks*8+2]=u0.z; areg[ks*8+3]=u0.w;
      areg[ks*8+4]=u1.x; areg[ks*8+5]=u1.y; areg[ks*8+6]=u1.z; areg[ks*8+7]=u1.w;
    }
    float ksq = 0.f;
    #pragma unroll
    for(int e=0;e<16;e++) ksq = fmaf(areg[e], areg[e], ksq);
    ksq += __shfl_xor(ksq, 16);
    ksq += __shfl_xor(ksq, 32);
    ksq *= 0.5f;
    short8 ah[2], al[2];
    #pragma unroll
    for(int ks=0;ks<2;ks++){
      #pragma unroll
      for(int j=0;j<8;j++){
        float x = areg[ks*8+j];
        u16 hb = f2b(x);
        ah[ks][j] = (short)hb;
        al[ks][j] = (short)f2b(x - b2f(hb));
      }
    }
    f32x4 acc[8];
    #pragma unroll
    for(int mt=0;mt<8;mt++) acc[mt] = zero4;
    #pragma unroll
    for(int ks=0;ks<2;ks++){
      #pragma unroll
      for(int mt=0;mt<8;mt++){
        acc[mt] = __builtin_amdgcn_mfma_f32_16x16x32_bf16(ah[ks], ph[mt][ks], acc[mt], 0, 0, 0);
        acc[mt] = __builtin_amdgcn_mfma_f32_16x16x32_bf16(ah[ks], pl[mt][ks], acc[mt], 0, 0, 0);
        acc[mt] = __builtin_amdgcn_mfma_f32_16x16x32_bf16(al[ks], ph[mt][ks], acc[mt], 0, 0, 0);
      }
    }
    const float kc0 = __shfl(ksq, 4*g + 0);
    const float kc1 = __shfl(ksq, 4*g + 1);
    const float kc2 = __shfl(ksq, 4*g + 2);
    const float kc3 = __shfl(ksq, 4*g + 3);
    #pragma unroll
    for(int mt=0;mt<8;mt++){
      ushort4 pw;
      pw.x = f2b(__expf(acc[mt][0] - kc0 - stab));
      pw.y = f2b(__expf(acc[mt][1] - kc1 - stab));
      pw.z = f2b(__expf(acc[mt][2] - kc2 - stab));
      pw.w = f2b(__expf(acc[mt][3] - kc3 - stab));
      *(ushort4*)(phit + (mt*16 + r16)*72 + wave*16 + 4*g) = pw;
    }
    __syncthreads();
    if(s_tile < 1056){
      const int m = tid & 127, kh = tid >> 7;
      for(int kk=0;kk<32;kk++){
        int skey = kh*32 + kk, gs = s_tile + skey;
        if(gs < 1056) phikg[(size_t)gs*128 + m] = phit[m*72 + skey];
      }
    }
    #pragma unroll
    for(int i=0;i<4;i++){
      int flat = tid + 256*i;
      int sv = flat >> 4, d4 = (flat & 15)*4;
      const float4 u = *(const float4*)(val + (size_t)(b*4096 + s_tile + sv)*512 + h*64 + d4);
      vt[(d4+0)*72 + sv] = f2b(u.x);
      vt[(d4+1)*72 + sv] = f2b(u.y);
      vt[(d4+2)*72 + sv] = f2b(u.z);
      vt[(d4+3)*72 + sv] = f2b(u.w);
    }
    __syncthreads();
    #pragma unroll
    for(int ks=0;ks<2;ks++){
      short8 af0 = *(const short8*)(phit + ((2*wave+0)*16 + r16)*72 + ks*32 + g*8);
      short8 af1 = *(const short8*)(phit + ((2*wave+1)*16 + r16)*72 + ks*32 + g*8);
      short8 bf[4];
      #pragma unroll
      for(int dt=0;dt<4;dt++) bf[dt] = *(const short8*)(vt + (dt*16 + r16)*72 + ks*32 + g*8);
      #pragma unroll
      for(int dt=0;dt<4;dt++){
        kvacc[0][dt] = __builtin_amdgcn_mfma_f32_16x16x32_bf16(af0, bf[dt], kvacc[0][dt], 0, 0, 0);
        kvacc[1][dt] = __builtin_amdgcn_mfma_f32_16x16x32_bf16(af1, bf[dt], kvacc[1][dt], 0, 0, 0);
      }
      #pragma unroll
      for(int j=0;j<8;j++){ k1p0 += b2f((u16)af0[j]); k1p1 += b2f((u16)af1[j]); }
    }
    __syncthreads();
  }
  k1p0 += __shfl_xor(k1p0, 16); k1p0 += __shfl_xor(k1p0, 32);
  k1p1 += __shfl_xor(k1p1, 16); k1p1 += __shfl_xor(k1p1, 32);
  if(l < 16){
    atomicAdd(ws + WS_K1 + combo*128 + (2*wave+0)*16 + l, k1p0);
    atomicAdd(ws + WS_K1 + combo*128 + (2*wave+1)*16 + l, k1p1);
  }
  #pragma unroll
  for(int mi=0;mi<2;mi++){
    #pragma unroll
    for(int dt=0;dt<4;dt++){
      #pragma unroll
      for(int rr=0;rr<4;rr++){
        int m = (2*wave+mi)*16 + 4*g + rr;
        int d = dt*16 + r16;
        atomicAdd(ws + WS_KV + (size_t)combo*8192 + m*64 + d, kvacc[mi][dt][rr]);
      }
    }
  }
}

// ================= k_q: logq MFMA -> phi_q/pls/lr1; lr_v = phi_q . kv MFMA =================
__global__ __launch_bounds__(256, 2) void k_q(const float* __restrict__ qry,
                                              const float* __restrict__ proj,
                                              float* __restrict__ ws){
  __shared__ __align__(16) u16 phiqs[64*136];  // [q][m] bf16, stride 136
  __shared__ __align__(16) u16 kvt[64*136];    // [d][m] bf16
  __shared__ float k1s[128];
  const int tid = threadIdx.x;
  const int wave = tid >> 6, l = tid & 63;
  const int g = l >> 4, r16 = l & 15;
  const int qt = blockIdx.x, combo = blockIdx.y;
  const int c = combo >> 5, b = (combo >> 3) & 3, h = combo & 7;
  const float* projc = proj + c*8192;
  const float stab = ws[WS_PMAX + combo];
  if(tid < 128) k1s[tid] = ws[WS_K1 + combo*128 + tid];
  const float* kvg = ws + WS_KV + (size_t)combo*8192;
  #pragma unroll
  for(int i=0;i<8;i++){
    int flat = tid + 256*i;
    int m = flat >> 4, d4 = (flat & 15)*4;
    float4 u = *(const float4*)(kvg + m*64 + d4);
    kvt[(d4+0)*136 + m] = f2b(u.x);
    kvt[(d4+1)*136 + m] = f2b(u.y);
    kvt[(d4+2)*136 + m] = f2b(u.z);
    kvt[(d4+3)*136 + m] = f2b(u.w);
  }
  const int qrow = qt*64 + wave*16 + r16;
  const float* qr = qry + (size_t)(b*4096 + (c*1024 + qrow))*512 + h*64;
  float areg[16];
  #pragma unroll
  for(int ks=0;ks<2;ks++){
    float4 u0 = *(const float4*)(qr + ks*32 + g*8);
    float4 u1 = *(const float4*)(qr + ks*32 + g*8 + 4);
    areg[ks*8+0]=u0.x; areg[ks*8+1]=u0.y; areg[ks*8+2]=u0.z; areg[ks*8+3]=u0.w;
    areg[ks*8+4]=u1.x; areg[ks*8+5]=u1.y; areg[ks*8+6]=u1.z; areg[ks*8+7]=u1.w;
  }
  float qsq = 0.f;
  #pragma unroll
  for(int e=0;e<16;e++) qsq = fmaf(areg[e], areg[e], qsq);
  qsq += __shfl_xor(qsq, 16);
  qsq += __shfl_xor(qsq, 32);
  qsq *= 0.5f;
  short8 ah[2], al[2];
  #pragma unroll
  for(int ks=0;ks<2;ks++){
    #pragma unroll
    for(int j=0;j<8;j++){
      float x = areg[ks*8+j];
      u16 hb = f2b(x);
      ah[ks][j] = (short)hb;
      al[ks][j] = (short)f2b(x - b2f(hb));
    }
  }
  const f32x4 zero4 = {0.f,0.f,0.f,0.f};
  f32x4 acc[8];
  #pragma unroll
  for(int mt=0;mt<8;mt++) acc[mt] = zero4;
  #pragma unroll
  for(int ks=0;ks<2;ks++){
    #pragma unroll
    for(int mt=0;mt<8;mt++){
      const float* pb = projc + (mt*16 + r16)*64 + ks*32 + g*8;
      float4 u0 = *(const float4*)pb;
      float4 u1 = *(const float4*)(pb + 4);
      float x[8] = {u0.x,u0.y,u0.z,u0.w,u1.x,u1.y,u1.z,u1.w};
      short8 pph, ppl;
      #pragma unroll
      for(int j=0;j<8;j++){
        u16 hb = f2b(x[j]);
        pph[j] = (short)hb;
        ppl[j] = (short)f2b(x[j] - b2f(hb));
      }
      acc[mt] = __builtin_amdgcn_mfma_f32_16x16x32_bf16(ah[ks], pph, acc[mt], 0, 0, 0);
      acc[mt] = __builtin_amdgcn_mfma_f32_16x16x32_bf16(ah[ks], ppl, acc[mt], 0, 0, 0);
      acc[mt] = __builtin_amdgcn_mfma_f32_16x16x32_bf16(al[ks], pph, acc[mt], 0, 0, 0);
    }
  }
  float qsr[4];
  #pragma unroll
  for(int r=0;r<4;r++) qsr[r] = __shfl(qsq, 4*g + r);
  float amax[4];
  #pragma unroll
  for(int r=0;r<4;r++){
    float m = -3e38f;
    #pragma unroll
    for(int mt=0;mt<8;mt++) m = fmaxf(m, acc[mt][r]);
    m = fmaxf(m, __shfl_xor(m, 1));
    m = fmaxf(m, __shfl_xor(m, 2));
    m = fmaxf(m, __shfl_xor(m, 4));
    m = fmaxf(m, __shfl_xor(m, 8));
    amax[r] = m;
  }
  float lrp[4] = {0.f,0.f,0.f,0.f};
  #pragma unroll
  for(int mt=0;mt<8;mt++){
    const float k1v = k1s[mt*16 + r16];
    #pragma unroll
    for(int r=0;r<4;r++){
      float phv = __expf(acc[mt][r] - amax[r]);
      phiqs[(wave*16 + 4*g + r)*136 + mt*16 + r16] = f2b(phv);
      lrp[r] = fmaf(phv, k1v, lrp[r]);
    }
  }
  #pragma unroll
  for(int r=0;r<4;r++){
    lrp[r] += __shfl_xor(lrp[r], 1);
    lrp[r] += __shfl_xor(lrp[r], 2);
    lrp[r] += __shfl_xor(lrp[r], 4);
    lrp[r] += __shfl_xor(lrp[r], 8);
  }
  if(r16 == 0){
    #pragma unroll
    for(int r=0;r<4;r++){
      int row = qt*64 + wave*16 + 4*g + r;
      ws[WS_PLS + combo*1024 + row] = amax[r] - qsr[r] + stab - LOGM;
      ws[WS_LR1 + combo*1024 + row] = lrp[r];
    }
  }
  __syncthreads();
  f32x4 lacc[4];
  #pragma unroll
  for(int dt=0;dt<4;dt++) lacc[dt] = zero4;
  #pragma unroll
  for(int ks=0;ks<4;ks++){
    short8 a = *(const short8*)(phiqs + (wave*16 + r16)*136 + ks*32 + g*8);
    #pragma unroll
    for(int dt=0;dt<4;dt++){
      short8 bfr = *(const short8*)(kvt + (dt*16 + r16)*136 + ks*32 + g*8);
      lacc[dt] = __builtin_amdgcn_mfma_f32_16x16x32_bf16(a, bfr, lacc[dt], 0, 0, 0);
    }
  }
  u16* lrvg = ((u16*)(ws + WS_LRV)) + ((size_t)combo*1024 + qt*64)*64;
  #pragma unroll
  for(int dt=0;dt<4;dt++){
    #pragma unroll
    for(int r=0;r<4;r++)
      lrvg[(wave*16 + 4*g + r)*64 + dt*16 + r16] = f2b(lacc[dt][r]);
  }
  u16* phiqg = ((u16*)(ws + WS_PHIQ)) + ((size_t)combo*1024 + qt*64)*128;
  #pragma unroll
  for(int i=0;i<8;i++){
    int flat = tid + 256*i;
    int row = flat >> 5, c4 = (flat & 31)*4;
    *(ushort4*)(phiqg + flat*4) = *(const ushort4*)(phiqs + row*136 + c4);
  }
}

// ================= k_main: local window + combine (no spills) =================
// grid (16 q-tiles of 64, 128 combos), 256 threads: 4 threads per query (h4 = tid&3)
__global__ __launch_bounds__(256) void k_main(const float* __restrict__ qry,
                                              const float* __restrict__ key,
                                              const float* __restrict__ val,
                                              float* __restrict__ ws,
                                              float* __restrict__ out){
  __shared__ __align__(16) u16 win[96*136];     // phi_k window [row][m] bf16
  __shared__ __align__(16) u16 phiqs[64*136];   // phi_q [q][m]; reused as cj[64][33] floats in pass 2
  const int tid = threadIdx.x;
  const int qt = blockIdx.x, combo = blockIdx.y;
  const int c = combo >> 5, b = (combo >> 3) & 3, h = combo & 7;
  // stage phi_q (coalesced)
  const u16* phiqg = ((const u16*)(ws + WS_PHIQ)) + ((size_t)combo*1024 + qt*64)*128;
  #pragma unroll
  for(int i=0;i<8;i++){
    int flat = tid + 256*i;
    int row = flat >> 5, c4 = (flat & 31)*4;
    *(ushort4*)(phiqs + row*136 + c4) = *(const ushort4*)(phiqg + flat*4);
  }
  // stage phi_k window rows [qt*64-16, qt*64+80)
  const int s_base = qt*64 - 16;
  const u16* phikg = ((const u16*)(ws + WS_PHIK)) + (size_t)combo*1056*128;
  #pragma unroll
  for(int i=0;i<12;i++){
    int flat = tid + 256*i;
    int row = flat >> 5, c4 = (flat & 31)*4;
    int gs = s_base + row;
    if(gs >= 0)
      *(ushort4*)(win + row*136 + c4) = *(const ushort4*)(phikg + (size_t)gs*128 + c4);
  }
  __syncthreads();
  const int l = tid >> 2, h4 = tid & 3;
  const int lg = qt*64 + l;
  const float4* qr = (const float4*)(qry + (((size_t)b*4096 + (c*1024 + lg))*8 + h)*64);
  float qreg[64];
  #pragma unroll
  for(int i=0;i<16;i++){
    float4 u = qr[i];
    qreg[4*i+0]=u.x; qreg[4*i+1]=u.y; qreg[4*i+2]=u.z; qreg[4*i+3]=u.w;
  }
  const float pls = ws[WS_PLS + combo*1024 + lg];
  const float lr1 = ws[WS_LR1 + combo*1024 + lg];
  const u16* myrow = phiqs + l*136;
  // pass 1: window scores + dots_p (this thread owns s = lg-16+h4*8 .. +8)
  float sc[8], dp[8];
  #pragma unroll
  for(int i=0;i<8;i++){
    const int s = lg - 16 + h4*8 + i;
    float sci = -1e30f, dpi = 0.f;
    if(s >= 0){
      const float4* kr = (const float4*)(key + (((size_t)b*4096 + s)*8 + h)*64);
      float d0=0.f,d1=0.f,d2=0.f,d3=0.f;
      #pragma unroll
      for(int t=0;t<16;t++){
        float4 u = kr[t];
        d0 = fmaf(qreg[4*t+0], u.x, d0);
        d1 = fmaf(qreg[4*t+1], u.y, d1);
        d2 = fmaf(qreg[4*t+2], u.z, d2);
        d3 = fmaf(qreg[4*t+3], u.w, d3);
      }
      sci = (d0+d1)+(d2+d3);
      const u16* pkrow = win + (s - s_base)*136;
      float e0=0.f,e1=0.f,e2=0.f,e3=0.f;
      #pragma unroll
      for(int t=0;t<16;t++){
        short8 a = *(const short8*)(myrow + 8*t);
        short8 bq = *(const short8*)(pkrow + 8*t);
        e0 = fmaf(b2f((u16)a[0]), b2f((u16)bq[0]), e0);
        e1 = fmaf(b2f((u16)a[1]), b2f((u16)bq[1]), e1);
        e2 = fmaf(b2f((u16)a[2]), b2f((u16)bq[2]), e2);
        e3 = fmaf(b2f((u16)a[3]), b2f((u16)bq[3]), e3);
        e0 = fmaf(b2f((u16)a[4]), b2f((u16)bq[4]), e0);
        e1 = fmaf(b2f((u16)a[5]), b2f((u16)bq[5]), e1);
        e2 = fmaf(b2f((u16)a[6]), b2f((u16)bq[6]), e2);
        e3 = fmaf(b2f((u16)a[7]), b2f((u16)bq[7]), e3);
      }
      dpi = (e0+e1)+(e2+e3);
    }
    sc[i] = sci; dp[i] = dpi;
  }
  // reductions across the query's 4 threads
  float m1 = sc[0];
  #pragma unroll
  for(int i=1;i<8;i++) m1 = fmaxf(m1, sc[i]);
  m1 = fmaxf(m1, __shfl_xor(m1, 1));
  m1 = fmaxf(m1, __shfl_xor(m1, 2));
  float se = 0.f, winp = 0.f;
  #pragma unroll
  for(int i=0;i<8;i++){ se += __expf(sc[i] - m1); winp += dp[i]; }
  se += __shfl_xor(se, 1);  se += __shfl_xor(se, 2);
  winp += __shfl_xor(winp, 1); winp += __shfl_xor(winp, 2);
  const float qk_lse = m1 + __logf(se);
  const float lrem = fmaxf(lr1 - winp, 1e-37f);
  const float bb = __logf(lrem) + pls;
  const float ln = fmaxf(qk_lse, bb) + log1pf(__expf(-fabsf(qk_lse - bb)));
  const float scale = __expf(pls - ln);
  // coefficients for this thread's 8 window keys
  float cj[8];
  #pragma unroll
  for(int i=0;i<8;i++){
    const int s = lg - 16 + h4*8 + i;
    cj[i] = (s >= 0) ? (__expf(sc[i] - ln) - scale * dp[i]) : 0.f;
  }
  __syncthreads();               // phiqs reads (myrow) done block-wide
  float* cjs = (float*)phiqs;    // [64][33] floats (8448 B < 17408 B)
  #pragma unroll
  for(int i=0;i<8;i++) cjs[l*33 + h4*8 + i] = cj[i];
  __syncthreads();
  // pass 2: thread (l,h4) accumulates its 16-element d-quarter over all 32 window keys
  float acc16[16];
  #pragma unroll
  for(int d=0;d<16;d++) acc16[d] = 0.f;
  for(int j=0;j<32;j++){
    const int s = lg - 16 + j;
    if(s >= 0){
      const float cv = cjs[l*33 + j];
      const float4* vr = (const float4*)(val + (((size_t)b*4096 + s)*8 + h)*64 + h4*16);
      #pragma unroll
      for(int t=0;t<4;t++){
        float4 u = vr[t];
        acc16[4*t+0] = fmaf(cv, u.x, acc16[4*t+0]);
        acc16[4*t+1] = fmaf(cv, u.y, acc16[4*t+1]);
        acc16[4*t+2] = fmaf(cv, u.z, acc16[4*t+2]);
        acc16[4*t+3] = fmaf(cv, u.w, acc16[4*t+3]);
      }
    }
  }
  // add scale * lr_v for this thread's d-quarter, write out (all static indices)
  const u16* lrvp = ((const u16*)(ws + WS_LRV)) + ((size_t)combo*1024 + lg)*64 + h4*16;
  float* ob = out + ((((size_t)b*8 + h)*4096) + (size_t)c*1024 + lg)*64 + h4*16;
  #pragma unroll
  for(int j=0;j<4;j++){
    ushort4 lv = *(const ushort4*)(lrvp + 4*j);
    float4 o;
    o.x = acc16[4*j + 0] + scale * b2f(lv.x);
    o.y = acc16[4*j + 1] + scale * b2f(lv.y);
    o.z = acc16[4*j + 2] + scale * b2f(lv.z);
    o.w = acc16[4*j + 3] + scale * b2f(lv.w);
    *(float4*)(ob + 4*j) = o;
  }
}

extern "C" void kernel_launch(void* const* d_in, const int* in_sizes, int n_in,
                              void* d_out, int out_size, void* d_ws, size_t ws_size,
                              hipStream_t stream){
  (void)in_sizes; (void)n_in; (void)out_size; (void)ws_size;
  const float* q = (const float*)d_in[0];
  const float* k = (const float*)d_in[1];
  const float* v = (const float*)d_in[2];
  const float* p = (const float*)d_in[3];
  float* out = (float*)d_out;
  float* ws = (float*)d_ws;
  hipMemsetAsync(ws + WS_K1, 0, (size_t)(16384 + 1048576)*sizeof(float), stream);
  k_phi <<<dim3(4,128),  256, 0, stream>>>(k, v, p, ws);
  k_q   <<<dim3(16,128), 256, 0, stream>>>(q, p, ws);
  k_main<<<dim3(16,128), 256, 0, stream>>>(q, k, v, ws, out);
}